// Round 17
// baseline (304.220 us; speedup 1.0000x reference)
//
#include <hip/hip_runtime.h>

#define NN 2
#define CC 32
#define NCC 4
#define DD 96
#define WW 96
#define HH 96
#define PP (DD*WW*HH)          // 884736
#define NCP (NN*NCC*PP)        // 7077888
#define SD (WW*HH)             // 9216
#define SW HH                  // 96
#define NCH (PP/1024)          // 864 pooldots chunks per n
#define PB  (PP/1024)          // 864 attn blocks per n
#define EPS 1e-5f
#define BIGF 1e30f

// Full-wave DPP sum (6 VALU adds, no DS traffic). Result in lane 63.
__device__ __forceinline__ float wave_reduce(float v) {
    v += __int_as_float(__builtin_amdgcn_update_dpp(0, __float_as_int(v), 0x111, 0xf, 0xf, true));
    v += __int_as_float(__builtin_amdgcn_update_dpp(0, __float_as_int(v), 0x112, 0xf, 0xf, true));
    v += __int_as_float(__builtin_amdgcn_update_dpp(0, __float_as_int(v), 0x114, 0xf, 0xf, true));
    v += __int_as_float(__builtin_amdgcn_update_dpp(0, __float_as_int(v), 0x118, 0xf, 0xf, true));
    v += __int_as_float(__builtin_amdgcn_update_dpp(0, __float_as_int(v), 0x142, 0xa, 0xf, true));
    v += __int_as_float(__builtin_amdgcn_update_dpp(0, __float_as_int(v), 0x143, 0xc, 0xf, true));
    return v;   // lane 63 holds the full 64-lane sum
}

// Row-16 DPP sum (4 VALU adds). Lanes 15/31/47/63 hold their row's sum.
__device__ __forceinline__ float row_reduce(float v) {
    v += __int_as_float(__builtin_amdgcn_update_dpp(0, __float_as_int(v), 0x111, 0xf, 0xf, true));
    v += __int_as_float(__builtin_amdgcn_update_dpp(0, __float_as_int(v), 0x112, 0xf, 0xf, true));
    v += __int_as_float(__builtin_amdgcn_update_dpp(0, __float_as_int(v), 0x114, 0xf, 0xf, true));
    v += __int_as_float(__builtin_amdgcn_update_dpp(0, __float_as_int(v), 0x118, 0xf, 0xf, true));
    return v;
}

__device__ __forceinline__ float dot4(float4 a, float4 b) {
    return a.x*b.x + a.y*b.y + a.z*b.z + a.w*b.w;
}

__device__ __forceinline__ float sigf(float v) { return 1.f / (1.f + __expf(-v)); }

__device__ __forceinline__ float4 max4f(float4 a, float4 b) {
    return make_float4(fmaxf(a.x,b.x), fmaxf(a.y,b.y), fmaxf(a.z,b.z), fmaxf(a.w,b.w));
}
__device__ __forceinline__ float4 min4f(float4 a, float4 b) {
    return make_float4(fminf(a.x,b.x), fminf(a.y,b.y), fminf(a.z,b.z), fminf(a.w,b.w));
}

// ---- K1: fused sigmoid + 1-D max pool along H. Writes mask + maxH only. ----
__global__ __launch_bounds__(256) void k_poolH(const float* __restrict__ x,
                                               float* __restrict__ mask,
                                               float* __restrict__ omax) {
    int i = (blockIdx.x * 256 + threadIdx.x) * 4;
    int h0 = i % HH;                       // multiple of 4
    float4 xv = *(const float4*)(x + i);
    float v0 = sigf(xv.x), v1 = sigf(xv.y), v2 = sigf(xv.z), v3 = sigf(xv.w);
    float aM = -BIGF, bM = -BIGF, cM = -BIGF, dM = -BIGF;
    if (h0 > 0)  { aM = sigf(x[i-2]); bM = sigf(x[i-1]); }
    if (h0 < 92) { cM = sigf(x[i+4]); dM = sigf(x[i+5]); }
    float4 mo = make_float4(v0, v1, v2, v3), mx;
    mx.x = fmaxf(fmaxf(aM, bM), fmaxf(fmaxf(v0, v1), v2));
    mx.y = fmaxf(bM, fmaxf(fmaxf(v0, v1), fmaxf(v2, v3)));
    mx.z = fmaxf(fmaxf(fmaxf(v0, v1), fmaxf(v2, v3)), cM);
    mx.w = fmaxf(fmaxf(v1, v2), fmaxf(v3, fmaxf(cM, dM)));
    *(float4*)(mask + i) = mo;
    *(float4*)(omax + i) = mx;
}

// ---- K2: fused W+D pools + feat dots. 1024-p chunk, 4 p/thread.
//      BRANCHLESS CLAMPED taps (dup rows are harmless for max/min) loaded
//      in batches of 5 into named regs -> high MLP, chains split per row.
//      Row-16 DPP reduce; sacc padded [296][17] (no bank conflicts). ----
__global__ __launch_bounds__(256, 2) void k_pooldots(const float* __restrict__ t0,
                                                     const float* __restrict__ mask,
                                                     const float* __restrict__ feat,
                                                     float* __restrict__ dotp) {
    __shared__ float sacc[296][17];                // padded: conflict-free tail
    int b = blockIdx.x;
    int n = b / NCH;
    int pt = (b % NCH) * 1024 + threadIdx.x * 4;   // intra-n offset
    int d  = pt / SD;
    int w  = (pt / SW) % WW;
    int h0 = pt % HH;                              // multiple of 4
    int wv = threadIdx.x >> 6, ln = threadIdx.x & 63;
    int rs = (wv << 2) | (ln >> 4);                // row-slot 0..15

    // clamped tap offsets (duplicate rows are no-ops for max/min)
    int od[5], ow[5];
    od[0] = (max(d-2, 0)    - d) * SD;
    od[1] = (max(d-1, 0)    - d) * SD;
    od[2] = 0;
    od[3] = (min(d+1, DD-1) - d) * SD;
    od[4] = (min(d+2, DD-1) - d) * SD;
    ow[0] = (max(w-2, 0)    - w) * SW;
    ow[1] = (max(w-1, 0)    - w) * SW;
    ow[2] = 0;
    ow[3] = (min(w+1, WW-1) - w) * SW;
    ow[4] = (min(w+2, WW-1) - w) * SW;

    float4 e[NCC], dv[NCC];
#pragma unroll
    for (int k = 0; k < NCC; ++k) {
        const size_t off = (size_t)(n*NCC + k)*PP + pt;
        // ---- dil: 25 unconditional loads, 5 independent row chains ----
        const float* tb = t0 + off;
        float4 r[5];
#pragma unroll
        for (int i = 0; i < 5; ++i) {
            const float* tp = tb + od[i];
            float4 a0 = *(const float4*)(tp + ow[0]);
            float4 a1 = *(const float4*)(tp + ow[1]);
            float4 a2 = *(const float4*)(tp + ow[2]);
            float4 a3 = *(const float4*)(tp + ow[3]);
            float4 a4 = *(const float4*)(tp + ow[4]);
            r[i] = max4f(max4f(a0, a1), max4f(a2, max4f(a3, a4)));
        }
        float4 mx = max4f(max4f(r[0], r[1]), max4f(r[2], max4f(r[3], r[4])));

        // ---- ero: H-window (branch only on h edges) + 4 W + 4 D taps ----
        const float* mb = mask + off;
        float4 m0 = *(const float4*)mb;
        float4 wA = *(const float4*)(mb + ow[0]);
        float4 wB = *(const float4*)(mb + ow[1]);
        float4 wC = *(const float4*)(mb + ow[3]);
        float4 wD = *(const float4*)(mb + ow[4]);
        float4 dA = *(const float4*)(mb + od[0]);
        float4 dB = *(const float4*)(mb + od[1]);
        float4 dC = *(const float4*)(mb + od[3]);
        float4 dD = *(const float4*)(mb + od[4]);
        float l0 = BIGF, l1 = BIGF, r0 = BIGF, r1 = BIGF;
        if (h0 > 0)  { l0 = mb[-2]; l1 = mb[-1]; }
        if (h0 < 92) { r0 = mb[4];  r1 = mb[5];  }
        float4 mnH;
        mnH.x = fminf(fminf(l0, l1),  fminf(m0.x, fminf(m0.y, m0.z)));
        mnH.y = fminf(l1, fminf(fminf(m0.x, m0.y), fminf(m0.z, m0.w)));
        mnH.z = fminf(fminf(m0.x, m0.y), fminf(m0.z, fminf(m0.w, r0)));
        mnH.w = fminf(fminf(m0.y, m0.z), fminf(m0.w, fminf(r0, r1)));
        float4 mnW = min4f(min4f(wA, wB), min4f(wC, wD));
        float4 mnD = min4f(min4f(dA, dB), min4f(dC, dD));
        float4 mn = min4f(mnH, min4f(mnW, mnD));

        e[k] = mn; dv[k] = mx;
        float th_e = row_reduce(mn.x + mn.y + mn.z + mn.w);
        float th_d = row_reduce(mx.x + mx.y + mx.z + mx.w);
        if ((ln & 15) == 15) {
            sacc[288 + k][rs] = th_e;
            sacc[292 + k][rs] = th_d;
        }
    }

    // feat dots, depth-1 prefetch
    const float* pf = feat + (size_t)(n*CC)*PP + pt;
    float4 fa = *(const float4*)pf;
    for (int c = 0; c < CC; ++c) {
        int cn = (c + 1 < CC) ? (c + 1) : c;
        float4 na = *(const float4*)(pf + (size_t)cn*PP);
        float vals[9];
#pragma unroll
        for (int k = 0; k < NCC; ++k) {
            vals[k]     = dot4(fa, e[k]);
            vals[4 + k] = dot4(fa, dv[k]);
        }
        vals[8] = fa.x + fa.y + fa.z + fa.w;
#pragma unroll
        for (int q = 0; q < 9; ++q) {
            float r = row_reduce(vals[q]);
            if ((ln & 15) == 15) sacc[c*9 + q][rs] = r;
        }
        fa = na;
    }
    __syncthreads();
    for (int i = threadIdx.x; i < 296; i += 256) {
        float s = 0.f;
#pragma unroll
        for (int j = 0; j < 16; ++j) s += sacc[i][j];
        dotp[(size_t)b*296 + i] = s;
    }
}

// ---- K3: stage-1 reduce of partials: 864 chunks -> 27 groups of 32. ----
__global__ __launch_bounds__(320) void k_dotred1(const float* __restrict__ dotp,
                                                 float* __restrict__ dotp2) {
    int t = threadIdx.x;
    if (t >= 296) return;
    int g = blockIdx.x;            // [0, NN*27)
    int n = g / 27, gg = g % 27;
    const float* p = dotp + (size_t)(n*NCH + gg*32)*296 + t;
    float s = 0.f;
#pragma unroll
    for (int j = 0; j < 32; ++j) s += p[(size_t)j*296];
    dotp2[(size_t)g*296 + t] = s;
}

// ---- K4: stage-2 reduce + cluster. grid = NN. ----
__global__ __launch_bounds__(320) void k_dotred2c(const float* __restrict__ dotp2,
                                                  float* __restrict__ cluster) {
    __shared__ float vals[296];
    int t = threadIdx.x;
    int n = blockIdx.x;
    if (t < 296) {
        float s = 0.f;
#pragma unroll
        for (int g = 0; g < 27; ++g) s += dotp2[((size_t)n*27 + g)*296 + t];
        vals[t] = s;
    }
    __syncthreads();
    if (t < NCC*CC) {
        int k = t >> 5, c = t & 31;
        float de = vals[c*9 + k];
        float dd = vals[c*9 + 4 + k];
        float fs = vals[c*9 + 8];
        float es = vals[288 + k] + EPS;
        float ds = vals[292 + k] + EPS;
        float bs = (float)PP - vals[292 + k] + EPS;
        cluster[((n*NCC + k)*CC + c)*2 + 0] = de/es + dd/ds;
        cluster[((n*NCC + k)*CC + c)*2 + 1] = (fs - dd)/bs;
    }
}

// ---- K5: attention BN-stats. Stores w0 weights; wave-private BN slots;
//      full DPP reduce, lane-63 write. ----
__global__ __launch_bounds__(256) void k_attn_stats(const float* __restrict__ feat,
                                                    const float* __restrict__ cluster,
                                                    const float* __restrict__ kptr,
                                                    float* __restrict__ w0a,
                                                    float* __restrict__ bnpart) {
    __shared__ float cl[NCC*CC*2];        // 256
    __shared__ float swp[4][CC*2];        // wave-private BN slots
    int b = blockIdx.x;
    int n = b / PB;
    int p0 = (b % PB) * 1024 + (threadIdx.x << 2);
    int wv = threadIdx.x >> 6, ln = threadIdx.x & 63;
    cl[threadIdx.x] = cluster[n*(NCC*CC*2) + threadIdx.x];
    __syncthreads();

    const float* fb = feat + (size_t)n*CC*PP + p0;

    float4 s0[NCC], s1[NCC];
#pragma unroll
    for (int k = 0; k < NCC; ++k) {
        s0[k] = make_float4(0.f, 0.f, 0.f, 0.f);
        s1[k] = make_float4(0.f, 0.f, 0.f, 0.f);
    }
    float4 fv = *(const float4*)fb;
    for (int c = 0; c < CC; ++c) {
        int cn = (c + 1 < CC) ? (c + 1) : c;
        float4 nv = *(const float4*)(fb + (size_t)cn*PP);
#pragma unroll
        for (int k = 0; k < NCC; ++k) {
            float2 cc2 = *(const float2*)&cl[(k*CC + c)*2];
            s0[k].x += fv.x*cc2.x; s0[k].y += fv.y*cc2.x;
            s0[k].z += fv.z*cc2.x; s0[k].w += fv.w*cc2.x;
            s1[k].x += fv.x*cc2.y; s1[k].y += fv.y*cc2.y;
            s1[k].z += fv.z*cc2.y; s1[k].w += fv.w*cc2.y;
        }
        fv = nv;
    }
    // softmax over 2 logits: w0 = sigmoid(s0-s1); store for apply pass
    float4 w0[NCC], w1[NCC];
#pragma unroll
    for (int k = 0; k < NCC; ++k) {
        w0[k].x = 1.f/(1.f + __expf(s1[k].x - s0[k].x));
        w0[k].y = 1.f/(1.f + __expf(s1[k].y - s0[k].y));
        w0[k].z = 1.f/(1.f + __expf(s1[k].z - s0[k].z));
        w0[k].w = 1.f/(1.f + __expf(s1[k].w - s0[k].w));
        w1[k].x = 1.f - w0[k].x; w1[k].y = 1.f - w0[k].y;
        w1[k].z = 1.f - w0[k].z; w1[k].w = 1.f - w0[k].w;
        *(float4*)(w0a + (size_t)(n*NCC + k)*PP + p0) = w0[k];
    }

    float kk = kptr[0];
#pragma unroll 8
    for (int c = 0; c < CC; ++c) {
        float4 f2 = *(const float4*)(fb + (size_t)c*PP);   // L2-hit re-read
        float4 a = make_float4(0.f, 0.f, 0.f, 0.f);
#pragma unroll
        for (int k = 0; k < NCC; ++k) {
            float2 cc2 = *(const float2*)&cl[(k*CC + c)*2];
            a.x += w0[k].x*cc2.x + w1[k].x*cc2.y;
            a.y += w0[k].y*cc2.x + w1[k].y*cc2.y;
            a.z += w0[k].z*cc2.x + w1[k].z*cc2.y;
            a.w += w0[k].w*cc2.x + w1[k].w*cc2.y;
        }
        float4 o;
        o.x = 5.f*f2.x + kk*a.x; o.y = 5.f*f2.y + kk*a.y;
        o.z = 5.f*f2.z + kk*a.z; o.w = 5.f*f2.w + kk*a.w;
        float ls = o.x + o.y + o.z + o.w;
        float lq = o.x*o.x + o.y*o.y + o.z*o.z + o.w*o.w;
        ls = wave_reduce(ls);
        lq = wave_reduce(lq);
        if (ln == 63) { swp[wv][2*c] = ls; swp[wv][2*c + 1] = lq; }
    }
    __syncthreads();
    if (threadIdx.x < CC*2)
        bnpart[(size_t)b*(CC*2) + threadIdx.x] =
            swp[0][threadIdx.x] + swp[1][threadIdx.x] +
            swp[2][threadIdx.x] + swp[3][threadIdx.x];
}

// ---- K6: reduce BN partials -> scale/shift. grid = CC blocks. ----
__global__ __launch_bounds__(256) void k_bnred(const float* __restrict__ bnpart,
                                               const float* __restrict__ wgt,
                                               const float* __restrict__ bias,
                                               float* __restrict__ scale,
                                               float* __restrict__ shift) {
    int c = blockIdx.x;
    float s = 0.f, q = 0.f;
    for (int b = threadIdx.x; b < NN*PB; b += 256) {
        s += bnpart[(size_t)b*(CC*2) + c*2];
        q += bnpart[(size_t)b*(CC*2) + c*2 + 1];
    }
    s = wave_reduce(s); q = wave_reduce(q);
    __shared__ float a[4], bb[4];
    if ((threadIdx.x & 63) == 63) { a[threadIdx.x >> 6] = s; bb[threadIdx.x >> 6] = q; }
    __syncthreads();
    if (threadIdx.x == 0) {
        float ts = a[0]+a[1]+a[2]+a[3];
        float tq = bb[0]+bb[1]+bb[2]+bb[3];
        float inv_n = 1.f / (float)((size_t)NN * PP);
        float mean = ts * inv_n;
        float var  = tq * inv_n - mean*mean;
        float inv  = 1.f / sqrtf(var + EPS);
        float sc = wgt[c] * inv;
        scale[c] = sc;
        shift[c] = bias[c] - mean*sc;
    }
}

// ---- K7: attention apply. Reads stored w0 — NO logit recompute. ----
__global__ __launch_bounds__(256) void k_attn_apply(const float* __restrict__ feat,
                                                    const float* __restrict__ w0a,
                                                    const float* __restrict__ cluster,
                                                    const float* __restrict__ kptr,
                                                    const float* __restrict__ scale,
                                                    const float* __restrict__ shift,
                                                    float* __restrict__ out) {
    __shared__ float cl[NCC*CC*2];
    __shared__ float ssc[CC], ssh[CC];
    int b = blockIdx.x;
    int n = b / PB;
    int p0 = (b % PB) * 1024 + (threadIdx.x << 2);
    cl[threadIdx.x] = cluster[n*(NCC*CC*2) + threadIdx.x];
    if (threadIdx.x < CC) {
        ssc[threadIdx.x] = scale[threadIdx.x];
        ssh[threadIdx.x] = shift[threadIdx.x];
    }
    __syncthreads();

    float4 w0[NCC], w1[NCC];
#pragma unroll
    for (int k = 0; k < NCC; ++k) {
        w0[k] = *(const float4*)(w0a + (size_t)(n*NCC + k)*PP + p0);
        w1[k].x = 1.f - w0[k].x; w1[k].y = 1.f - w0[k].y;
        w1[k].z = 1.f - w0[k].z; w1[k].w = 1.f - w0[k].w;
    }

    float kk = kptr[0];
    const float* fb = feat + (size_t)n*CC*PP + p0;
    float* ob = out + (size_t)n*CC*PP + p0;
    float4 fv = *(const float4*)fb;
    for (int c = 0; c < CC; ++c) {
        int cn = (c + 1 < CC) ? (c + 1) : c;
        float4 nv = *(const float4*)(fb + (size_t)cn*PP);
        float4 a = make_float4(0.f, 0.f, 0.f, 0.f);
#pragma unroll
        for (int k = 0; k < NCC; ++k) {
            float2 cc2 = *(const float2*)&cl[(k*CC + c)*2];
            a.x += w0[k].x*cc2.x + w1[k].x*cc2.y;
            a.y += w0[k].y*cc2.x + w1[k].y*cc2.y;
            a.z += w0[k].z*cc2.x + w1[k].z*cc2.y;
            a.w += w0[k].w*cc2.x + w1[k].w*cc2.y;
        }
        float sc = ssc[c], sh = ssh[c];
        float4 o;
        o.x = (5.f*fv.x + kk*a.x)*sc + sh;
        o.y = (5.f*fv.y + kk*a.y)*sc + sh;
        o.z = (5.f*fv.z + kk*a.z)*sc + sh;
        o.w = (5.f*fv.w + kk*a.w)*sc + sh;
        *(float4*)(ob + (size_t)c*PP) = o;
        fv = nv;
    }
}

extern "C" void kernel_launch(void* const* d_in, const int* in_sizes, int n_in,
                              void* d_out, int out_size, void* d_ws, size_t ws_size,
                              hipStream_t stream) {
    const float* feat = (const float*)d_in[0];
    const float* x    = (const float*)d_in[1];
    const float* kp   = (const float*)d_in[2];
    const float* bnw  = (const float*)d_in[3];
    const float* bnb  = (const float*)d_in[4];
    float* out = (float*)d_out;
    float* ws  = (float*)d_ws;

    float* mask    = ws;                         // NCP
    float* t0      = ws + 1*(size_t)NCP;         // NCP (maxH)
    float* w0a     = ws + 2*(size_t)NCP;         // NCP (softmax w0 weights)
    float* scratch = ws + 3*(size_t)NCP;
    float* dotp    = scratch;                    // 1728*296 = 511488
    float* dotp2   = scratch + 524288;           // 54*296  = 15984
    float* bnpart  = scratch + 540672;           // 1728*64 = 110592
    float* acc     = scratch + 655360;
    float* cluster = acc;                        // 512
    float* scale   = acc + 512;                  // 32
    float* shift   = acc + 544;                  // 32

    k_poolH     <<<NCP/1024, 256, 0, stream>>>(x, mask, t0);
    k_pooldots  <<<NN*NCH, 256, 0, stream>>>(t0, mask, feat, dotp);
    k_dotred1   <<<NN*27, 320, 0, stream>>>(dotp, dotp2);
    k_dotred2c  <<<NN, 320, 0, stream>>>(dotp2, cluster);
    k_attn_stats<<<NN*PB, 256, 0, stream>>>(feat, cluster, kp, w0a, bnpart);
    k_bnred     <<<CC, 256, 0, stream>>>(bnpart, bnw, bnb, scale, shift);
    k_attn_apply<<<NN*PB, 256, 0, stream>>>(feat, w0a, cluster, kp, scale, shift, out);
}

// Round 18
// 294.106 us; speedup vs baseline: 1.0344x; 1.0344x over previous
//
#include <hip/hip_runtime.h>

#define NN 2
#define CC 32
#define NCC 4
#define DD 96
#define WW 96
#define HH 96
#define PP (DD*WW*HH)          // 884736
#define NCP (NN*NCC*PP)        // 7077888
#define SD (WW*HH)             // 9216
#define SW HH                  // 96
#define NCH (PP/1024)          // 864 pooldots chunks per n
#define PB  (PP/1024)          // 864 attn blocks per n
#define EPS 1e-5f
#define BIGF 1e30f

// Full-wave DPP sum (6 VALU adds, no DS traffic). Result in lane 63.
__device__ __forceinline__ float wave_reduce(float v) {
    v += __int_as_float(__builtin_amdgcn_update_dpp(0, __float_as_int(v), 0x111, 0xf, 0xf, true));
    v += __int_as_float(__builtin_amdgcn_update_dpp(0, __float_as_int(v), 0x112, 0xf, 0xf, true));
    v += __int_as_float(__builtin_amdgcn_update_dpp(0, __float_as_int(v), 0x114, 0xf, 0xf, true));
    v += __int_as_float(__builtin_amdgcn_update_dpp(0, __float_as_int(v), 0x118, 0xf, 0xf, true));
    v += __int_as_float(__builtin_amdgcn_update_dpp(0, __float_as_int(v), 0x142, 0xa, 0xf, true));
    v += __int_as_float(__builtin_amdgcn_update_dpp(0, __float_as_int(v), 0x143, 0xc, 0xf, true));
    return v;   // lane 63 holds the full 64-lane sum
}

// Row-16 DPP sum (4 VALU adds). Lanes 15/31/47/63 hold their row's sum.
__device__ __forceinline__ float row_reduce(float v) {
    v += __int_as_float(__builtin_amdgcn_update_dpp(0, __float_as_int(v), 0x111, 0xf, 0xf, true));
    v += __int_as_float(__builtin_amdgcn_update_dpp(0, __float_as_int(v), 0x112, 0xf, 0xf, true));
    v += __int_as_float(__builtin_amdgcn_update_dpp(0, __float_as_int(v), 0x114, 0xf, 0xf, true));
    v += __int_as_float(__builtin_amdgcn_update_dpp(0, __float_as_int(v), 0x118, 0xf, 0xf, true));
    return v;
}

__device__ __forceinline__ float dot4(float4 a, float4 b) {
    return a.x*b.x + a.y*b.y + a.z*b.z + a.w*b.w;
}

__device__ __forceinline__ float sigf(float v) { return 1.f / (1.f + __expf(-v)); }

__device__ __forceinline__ void max4v(float4& x, const float* p) {
    float4 a = *(const float4*)p;
    x.x = fmaxf(x.x, a.x); x.y = fmaxf(x.y, a.y);
    x.z = fmaxf(x.z, a.z); x.w = fmaxf(x.w, a.w);
}

__device__ __forceinline__ void min4v(float4& x, const float* p) {
    float4 a = *(const float4*)p;
    x.x = fminf(x.x, a.x); x.y = fminf(x.y, a.y);
    x.z = fminf(x.z, a.z); x.w = fminf(x.w, a.w);
}

// ---- K1: fused sigmoid + 1-D max pool along H. Writes mask + maxH only. ----
__global__ __launch_bounds__(256) void k_poolH(const float* __restrict__ x,
                                               float* __restrict__ mask,
                                               float* __restrict__ omax) {
    int i = (blockIdx.x * 256 + threadIdx.x) * 4;
    int h0 = i % HH;                       // multiple of 4
    float4 xv = *(const float4*)(x + i);
    float v0 = sigf(xv.x), v1 = sigf(xv.y), v2 = sigf(xv.z), v3 = sigf(xv.w);
    float aM = -BIGF, bM = -BIGF, cM = -BIGF, dM = -BIGF;
    if (h0 > 0)  { aM = sigf(x[i-2]); bM = sigf(x[i-1]); }
    if (h0 < 92) { cM = sigf(x[i+4]); dM = sigf(x[i+5]); }
    float4 mo = make_float4(v0, v1, v2, v3), mx;
    mx.x = fmaxf(fmaxf(aM, bM), fmaxf(fmaxf(v0, v1), v2));
    mx.y = fmaxf(bM, fmaxf(fmaxf(v0, v1), fmaxf(v2, v3)));
    mx.z = fmaxf(fmaxf(fmaxf(v0, v1), fmaxf(v2, v3)), cM);
    mx.w = fmaxf(fmaxf(v1, v2), fmaxf(v3, fmaxf(cM, dM)));
    *(float4*)(mask + i) = mo;
    *(float4*)(omax + i) = mx;
}

// ---- K2: fused W+D pools + feat dots (R16 best structure: 1024-p chunk,
//      4 p/thread, row-16 DPP reduce) + clamped branchless taps (loop form,
//      low VGPR) + padded sacc (conflict-free tail). ----
__global__ __launch_bounds__(256, 2) void k_pooldots(const float* __restrict__ t0,
                                                     const float* __restrict__ mask,
                                                     const float* __restrict__ feat,
                                                     float* __restrict__ dotp) {
    __shared__ float sacc[296][17];                // padded: conflict-free tail
    int b = blockIdx.x;
    int n = b / NCH;
    int pt = (b % NCH) * 1024 + threadIdx.x * 4;   // intra-n offset
    int d  = pt / SD;
    int w  = (pt / SW) % WW;
    int h0 = pt % HH;                              // multiple of 4
    int wv = threadIdx.x >> 6, ln = threadIdx.x & 63;
    int rs = (wv << 2) | (ln >> 4);                // row-slot 0..15

    // clamped tap offsets: duplicate rows are no-ops for max/min pooling
    int od[5], ow[5];
    od[0] = (max(d-2, 0)    - d) * SD;
    od[1] = (max(d-1, 0)    - d) * SD;
    od[2] = 0;
    od[3] = (min(d+1, DD-1) - d) * SD;
    od[4] = (min(d+2, DD-1) - d) * SD;
    ow[0] = (max(w-2, 0)    - w) * SW;
    ow[1] = (max(w-1, 0)    - w) * SW;
    ow[2] = 0;
    ow[3] = (min(w+1, WW-1) - w) * SW;
    ow[4] = (min(w+2, WW-1) - w) * SW;

    float4 e[NCC], dv[NCC];
#pragma unroll
    for (int k = 0; k < NCC; ++k) {
        const size_t off = (size_t)(n*NCC + k)*PP + pt;
        // dil = max over 25 clamped (dd,ww) taps of maxH — branchless
        const float* tb = t0 + off;
        float4 mx = make_float4(-BIGF,-BIGF,-BIGF,-BIGF);
#pragma unroll
        for (int i = 0; i < 5; ++i) {
            const float* tp = tb + od[i];
#pragma unroll
            for (int j = 0; j < 5; ++j) max4v(mx, tp + ow[j]);
        }
        // ero = min(minH, minW, minD) of mask — W/D taps branchless
        const float* mb = mask + off;
        float4 m0 = *(const float4*)mb;
        float l0 = BIGF, l1 = BIGF, r0 = BIGF, r1 = BIGF;
        if (h0 > 0)  { l0 = mb[-2]; l1 = mb[-1]; }
        if (h0 < 92) { r0 = mb[4];  r1 = mb[5];  }
        float4 mn;
        mn.x = fminf(fminf(l0, l1),  fminf(m0.x, fminf(m0.y, m0.z)));
        mn.y = fminf(l1, fminf(fminf(m0.x, m0.y), fminf(m0.z, m0.w)));
        mn.z = fminf(fminf(m0.x, m0.y), fminf(m0.z, fminf(m0.w, r0)));
        mn.w = fminf(fminf(m0.y, m0.z), fminf(m0.w, fminf(r0, r1)));
        min4v(mn, mb + ow[0]);
        min4v(mn, mb + ow[1]);
        min4v(mn, mb + ow[3]);
        min4v(mn, mb + ow[4]);
        min4v(mn, mb + od[0]);
        min4v(mn, mb + od[1]);
        min4v(mn, mb + od[3]);
        min4v(mn, mb + od[4]);

        e[k] = mn; dv[k] = mx;
        float th_e = row_reduce(mn.x + mn.y + mn.z + mn.w);
        float th_d = row_reduce(mx.x + mx.y + mx.z + mx.w);
        if ((ln & 15) == 15) {
            sacc[288 + k][rs] = th_e;
            sacc[292 + k][rs] = th_d;
        }
    }

    // feat dots, depth-1 prefetch
    const float* pf = feat + (size_t)(n*CC)*PP + pt;
    float4 fa = *(const float4*)pf;
    for (int c = 0; c < CC; ++c) {
        int cn = (c + 1 < CC) ? (c + 1) : c;
        float4 na = *(const float4*)(pf + (size_t)cn*PP);
        float vals[9];
#pragma unroll
        for (int k = 0; k < NCC; ++k) {
            vals[k]     = dot4(fa, e[k]);
            vals[4 + k] = dot4(fa, dv[k]);
        }
        vals[8] = fa.x + fa.y + fa.z + fa.w;
#pragma unroll
        for (int q = 0; q < 9; ++q) {
            float r = row_reduce(vals[q]);
            if ((ln & 15) == 15) sacc[c*9 + q][rs] = r;
        }
        fa = na;
    }
    __syncthreads();
    for (int i = threadIdx.x; i < 296; i += 256) {
        float s = 0.f;
#pragma unroll
        for (int j = 0; j < 16; ++j) s += sacc[i][j];
        dotp[(size_t)b*296 + i] = s;
    }
}

// ---- K3: stage-1 reduce of partials: 864 chunks -> 27 groups of 32. ----
__global__ __launch_bounds__(320) void k_dotred1(const float* __restrict__ dotp,
                                                 float* __restrict__ dotp2) {
    int t = threadIdx.x;
    if (t >= 296) return;
    int g = blockIdx.x;            // [0, NN*27)
    int n = g / 27, gg = g % 27;
    const float* p = dotp + (size_t)(n*NCH + gg*32)*296 + t;
    float s = 0.f;
#pragma unroll
    for (int j = 0; j < 32; ++j) s += p[(size_t)j*296];
    dotp2[(size_t)g*296 + t] = s;
}

// ---- K4: stage-2 reduce + cluster. grid = NN. ----
__global__ __launch_bounds__(320) void k_dotred2c(const float* __restrict__ dotp2,
                                                  float* __restrict__ cluster) {
    __shared__ float vals[296];
    int t = threadIdx.x;
    int n = blockIdx.x;
    if (t < 296) {
        float s = 0.f;
#pragma unroll
        for (int g = 0; g < 27; ++g) s += dotp2[((size_t)n*27 + g)*296 + t];
        vals[t] = s;
    }
    __syncthreads();
    if (t < NCC*CC) {
        int k = t >> 5, c = t & 31;
        float de = vals[c*9 + k];
        float dd = vals[c*9 + 4 + k];
        float fs = vals[c*9 + 8];
        float es = vals[288 + k] + EPS;
        float ds = vals[292 + k] + EPS;
        float bs = (float)PP - vals[292 + k] + EPS;
        cluster[((n*NCC + k)*CC + c)*2 + 0] = de/es + dd/ds;
        cluster[((n*NCC + k)*CC + c)*2 + 1] = (fs - dd)/bs;
    }
}

// ---- K5: attention BN-stats. Stores w0 weights; wave-private BN slots;
//      full DPP reduce, lane-63 write. ----
__global__ __launch_bounds__(256) void k_attn_stats(const float* __restrict__ feat,
                                                    const float* __restrict__ cluster,
                                                    const float* __restrict__ kptr,
                                                    float* __restrict__ w0a,
                                                    float* __restrict__ bnpart) {
    __shared__ float cl[NCC*CC*2];        // 256
    __shared__ float swp[4][CC*2];        // wave-private BN slots
    int b = blockIdx.x;
    int n = b / PB;
    int p0 = (b % PB) * 1024 + (threadIdx.x << 2);
    int wv = threadIdx.x >> 6, ln = threadIdx.x & 63;
    cl[threadIdx.x] = cluster[n*(NCC*CC*2) + threadIdx.x];
    __syncthreads();

    const float* fb = feat + (size_t)n*CC*PP + p0;

    float4 s0[NCC], s1[NCC];
#pragma unroll
    for (int k = 0; k < NCC; ++k) {
        s0[k] = make_float4(0.f, 0.f, 0.f, 0.f);
        s1[k] = make_float4(0.f, 0.f, 0.f, 0.f);
    }
    float4 fv = *(const float4*)fb;
    for (int c = 0; c < CC; ++c) {
        int cn = (c + 1 < CC) ? (c + 1) : c;
        float4 nv = *(const float4*)(fb + (size_t)cn*PP);
#pragma unroll
        for (int k = 0; k < NCC; ++k) {
            float2 cc2 = *(const float2*)&cl[(k*CC + c)*2];
            s0[k].x += fv.x*cc2.x; s0[k].y += fv.y*cc2.x;
            s0[k].z += fv.z*cc2.x; s0[k].w += fv.w*cc2.x;
            s1[k].x += fv.x*cc2.y; s1[k].y += fv.y*cc2.y;
            s1[k].z += fv.z*cc2.y; s1[k].w += fv.w*cc2.y;
        }
        fv = nv;
    }
    // softmax over 2 logits: w0 = sigmoid(s0-s1); store for apply pass
    float4 w0[NCC], w1[NCC];
#pragma unroll
    for (int k = 0; k < NCC; ++k) {
        w0[k].x = 1.f/(1.f + __expf(s1[k].x - s0[k].x));
        w0[k].y = 1.f/(1.f + __expf(s1[k].y - s0[k].y));
        w0[k].z = 1.f/(1.f + __expf(s1[k].z - s0[k].z));
        w0[k].w = 1.f/(1.f + __expf(s1[k].w - s0[k].w));
        w1[k].x = 1.f - w0[k].x; w1[k].y = 1.f - w0[k].y;
        w1[k].z = 1.f - w0[k].z; w1[k].w = 1.f - w0[k].w;
        *(float4*)(w0a + (size_t)(n*NCC + k)*PP + p0) = w0[k];
    }

    float kk = kptr[0];
#pragma unroll 8
    for (int c = 0; c < CC; ++c) {
        float4 f2 = *(const float4*)(fb + (size_t)c*PP);   // L2-hit re-read
        float4 a = make_float4(0.f, 0.f, 0.f, 0.f);
#pragma unroll
        for (int k = 0; k < NCC; ++k) {
            float2 cc2 = *(const float2*)&cl[(k*CC + c)*2];
            a.x += w0[k].x*cc2.x + w1[k].x*cc2.y;
            a.y += w0[k].y*cc2.x + w1[k].y*cc2.y;
            a.z += w0[k].z*cc2.x + w1[k].z*cc2.y;
            a.w += w0[k].w*cc2.x + w1[k].w*cc2.y;
        }
        float4 o;
        o.x = 5.f*f2.x + kk*a.x; o.y = 5.f*f2.y + kk*a.y;
        o.z = 5.f*f2.z + kk*a.z; o.w = 5.f*f2.w + kk*a.w;
        float ls = o.x + o.y + o.z + o.w;
        float lq = o.x*o.x + o.y*o.y + o.z*o.z + o.w*o.w;
        ls = wave_reduce(ls);
        lq = wave_reduce(lq);
        if (ln == 63) { swp[wv][2*c] = ls; swp[wv][2*c + 1] = lq; }
    }
    __syncthreads();
    if (threadIdx.x < CC*2)
        bnpart[(size_t)b*(CC*2) + threadIdx.x] =
            swp[0][threadIdx.x] + swp[1][threadIdx.x] +
            swp[2][threadIdx.x] + swp[3][threadIdx.x];
}

// ---- K6: reduce BN partials -> scale/shift. grid = CC blocks. ----
__global__ __launch_bounds__(256) void k_bnred(const float* __restrict__ bnpart,
                                               const float* __restrict__ wgt,
                                               const float* __restrict__ bias,
                                               float* __restrict__ scale,
                                               float* __restrict__ shift) {
    int c = blockIdx.x;
    float s = 0.f, q = 0.f;
    for (int b = threadIdx.x; b < NN*PB; b += 256) {
        s += bnpart[(size_t)b*(CC*2) + c*2];
        q += bnpart[(size_t)b*(CC*2) + c*2 + 1];
    }
    s = wave_reduce(s); q = wave_reduce(q);
    __shared__ float a[4], bb[4];
    if ((threadIdx.x & 63) == 63) { a[threadIdx.x >> 6] = s; bb[threadIdx.x >> 6] = q; }
    __syncthreads();
    if (threadIdx.x == 0) {
        float ts = a[0]+a[1]+a[2]+a[3];
        float tq = bb[0]+bb[1]+bb[2]+bb[3];
        float inv_n = 1.f / (float)((size_t)NN * PP);
        float mean = ts * inv_n;
        float var  = tq * inv_n - mean*mean;
        float inv  = 1.f / sqrtf(var + EPS);
        float sc = wgt[c] * inv;
        scale[c] = sc;
        shift[c] = bias[c] - mean*sc;
    }
}

// ---- K7: attention apply. Reads stored w0 — NO logit recompute. ----
__global__ __launch_bounds__(256) void k_attn_apply(const float* __restrict__ feat,
                                                    const float* __restrict__ w0a,
                                                    const float* __restrict__ cluster,
                                                    const float* __restrict__ kptr,
                                                    const float* __restrict__ scale,
                                                    const float* __restrict__ shift,
                                                    float* __restrict__ out) {
    __shared__ float cl[NCC*CC*2];
    __shared__ float ssc[CC], ssh[CC];
    int b = blockIdx.x;
    int n = b / PB;
    int p0 = (b % PB) * 1024 + (threadIdx.x << 2);
    cl[threadIdx.x] = cluster[n*(NCC*CC*2) + threadIdx.x];
    if (threadIdx.x < CC) {
        ssc[threadIdx.x] = scale[threadIdx.x];
        ssh[threadIdx.x] = shift[threadIdx.x];
    }
    __syncthreads();

    float4 w0[NCC], w1[NCC];
#pragma unroll
    for (int k = 0; k < NCC; ++k) {
        w0[k] = *(const float4*)(w0a + (size_t)(n*NCC + k)*PP + p0);
        w1[k].x = 1.f - w0[k].x; w1[k].y = 1.f - w0[k].y;
        w1[k].z = 1.f - w0[k].z; w1[k].w = 1.f - w0[k].w;
    }

    float kk = kptr[0];
    const float* fb = feat + (size_t)n*CC*PP + p0;
    float* ob = out + (size_t)n*CC*PP + p0;
    float4 fv = *(const float4*)fb;
    for (int c = 0; c < CC; ++c) {
        int cn = (c + 1 < CC) ? (c + 1) : c;
        float4 nv = *(const float4*)(fb + (size_t)cn*PP);
        float4 a = make_float4(0.f, 0.f, 0.f, 0.f);
#pragma unroll
        for (int k = 0; k < NCC; ++k) {
            float2 cc2 = *(const float2*)&cl[(k*CC + c)*2];
            a.x += w0[k].x*cc2.x + w1[k].x*cc2.y;
            a.y += w0[k].y*cc2.x + w1[k].y*cc2.y;
            a.z += w0[k].z*cc2.x + w1[k].z*cc2.y;
            a.w += w0[k].w*cc2.x + w1[k].w*cc2.y;
        }
        float sc = ssc[c], sh = ssh[c];
        float4 o;
        o.x = (5.f*fv.x + kk*a.x)*sc + sh;
        o.y = (5.f*fv.y + kk*a.y)*sc + sh;
        o.z = (5.f*fv.z + kk*a.z)*sc + sh;
        o.w = (5.f*fv.w + kk*a.w)*sc + sh;
        *(float4*)(ob + (size_t)c*PP) = o;
        fv = nv;
    }
}

extern "C" void kernel_launch(void* const* d_in, const int* in_sizes, int n_in,
                              void* d_out, int out_size, void* d_ws, size_t ws_size,
                              hipStream_t stream) {
    const float* feat = (const float*)d_in[0];
    const float* x    = (const float*)d_in[1];
    const float* kp   = (const float*)d_in[2];
    const float* bnw  = (const float*)d_in[3];
    const float* bnb  = (const float*)d_in[4];
    float* out = (float*)d_out;
    float* ws  = (float*)d_ws;

    float* mask    = ws;                         // NCP
    float* t0      = ws + 1*(size_t)NCP;         // NCP (maxH)
    float* w0a     = ws + 2*(size_t)NCP;         // NCP (softmax w0 weights)
    float* scratch = ws + 3*(size_t)NCP;
    float* dotp    = scratch;                    // 1728*296 = 511488
    float* dotp2   = scratch + 524288;           // 54*296  = 15984
    float* bnpart  = scratch + 540672;           // 1728*64 = 110592
    float* acc     = scratch + 655360;
    float* cluster = acc;                        // 512
    float* scale   = acc + 512;                  // 32
    float* shift   = acc + 544;                  // 32

    k_poolH     <<<NCP/1024, 256, 0, stream>>>(x, mask, t0);
    k_pooldots  <<<NN*NCH, 256, 0, stream>>>(t0, mask, feat, dotp);
    k_dotred1   <<<NN*27, 320, 0, stream>>>(dotp, dotp2);
    k_dotred2c  <<<NN, 320, 0, stream>>>(dotp2, cluster);
    k_attn_stats<<<NN*PB, 256, 0, stream>>>(feat, cluster, kp, w0a, bnpart);
    k_bnred     <<<CC, 256, 0, stream>>>(bnpart, bnw, bnb, scale, shift);
    k_attn_apply<<<NN*PB, 256, 0, stream>>>(feat, w0a, cluster, kp, scale, shift, out);
}